// Round 3
// baseline (293.642 us; speedup 1.0000x reference)
//
#include <hip/hip_runtime.h>
#include <hip/hip_bf16.h>
#include <math.h>

#define ROWS 256
#define DD 64
#define EE 8
#define HH 64
#define GHD 32

typedef __attribute__((ext_vector_type(8))) short bf16x8;
typedef __attribute__((ext_vector_type(4))) float f32x4;

static __device__ __forceinline__ short f2bf(float f) {
    unsigned u = __builtin_bit_cast(unsigned, f);
    unsigned r = (u + 0x7fffu + ((u >> 16) & 1u)) >> 16;  // round-to-nearest-even
    return (short)r;
}
static __device__ __forceinline__ float bf2f(unsigned short b) {
    unsigned u = ((unsigned)b) << 16;
    return __builtin_bit_cast(float, u);
}
// packed f32x2 -> bf16x2 (lowers to v_cvt_pk_bf16_f32, RNE — bit-identical to f2bf)
static __device__ __forceinline__ unsigned pk2(float lo, float hi) {
    __hip_bfloat162 h = __float22bfloat162_rn(make_float2(lo, hi));
    unsigned r;
    __builtin_memcpy(&r, &h, 4);
    return r;
}
// butterfly add via DPP (ctrl must be a compile-time constant)
template <int CTRL>
static __device__ __forceinline__ float dpp_add(float x) {
    int xi = __builtin_bit_cast(int, x);
    int yi = __builtin_amdgcn_update_dpp(0, xi, CTRL, 0xF, 0xF, true);
    return x + __builtin_bit_cast(float, yi);
}
// cross-lane add via ds_bpermute (addr = (lane^mask)<<2, precomputed)
static __device__ __forceinline__ float bperm_add(float x, int addr) {
    int xi = __builtin_bit_cast(int, x);
    int yi = __builtin_amdgcn_ds_bpermute(addr, xi);
    return x + __builtin_bit_cast(float, yi);
}

// Precompute W1 (experts) and gw1 (gating) as bf16 MFMA fragments in d_ws.
// expert frags (B-operand): idx = wave<<10 | tt<<7 | half<<6 | lane, 8 shorts each (64 KB)
// gating frags (A-operand of gw1^T): 2 tiles x 64 lanes x 8 shorts at short-offset 32768 (2 KB)
//   A[row=g][k=d] = gw1[d][g]; lane l holds row g = tile*16 + (l&15), k = (l>>4)*8+j.
// d_ws must be >= 67584 bytes.
__global__ __launch_bounds__(256) void prep_kernel(const float* __restrict__ ew1,
                                                   const float* __restrict__ gw1,
                                                   short* __restrict__ wf) {
    int idx = blockIdx.x * 256 + threadIdx.x;   // 4096 frags
    int lane = idx & 63;
    int half = (idx >> 6) & 1;
    int tt   = (idx >> 7) & 7;
    int wave = (idx >> 10) & 3;
    int n = wave * 128 + tt * 16 + (lane & 15);
    int e = n >> 6, h = n & 63;
    int quad = lane >> 4;
    short v[8];
    #pragma unroll
    for (int j = 0; j < 8; ++j) {
        int dl = quad * 8 + j + half * 32;
        v[j] = f2bf(ew1[(e * DD + dl) * HH + h]);
    }
    *(bf16x8*)(wf + (size_t)idx * 8) = *(const bf16x8*)v;
    if (idx < 128) {                            // gw1^T A-frags
        int tile = idx >> 6;
        int lr = lane & 15;
        short g[8];
        #pragma unroll
        for (int j = 0; j < 8; ++j)
            g[j] = f2bf(gw1[(quad * 8 + j) * GHD + tile * 16 + lr]);
        *(bf16x8*)(wf + 32768 + (size_t)idx * 8) = *(const bf16x8*)g;
    }
}

__global__ __launch_bounds__(256, 4) void moe_kernel(
    const float* __restrict__ A, const float* __restrict__ S,
    const float* __restrict__ gb1, const float* __restrict__ gw2,
    const float* __restrict__ gb2, const short* __restrict__ wf,
    const float* __restrict__ eb1, const float* __restrict__ ew2,
    const float* __restrict__ eb2, float* __restrict__ out)
{
    // xs row = 72 shorts (144 B): [0..63] bf16 x-data, [64..71] = 4 f32 result slots (1/wave).
    __shared__ __align__(16) short xs[ROWS][72];            // 36864 B
    __shared__ __align__(16) unsigned short psb[ROWS][EE];  // 4096 B (bf16 gating probs)
    // total 40960 B -> 4 blocks/CU

    const int t = threadIdx.x;
    const int row0 = blockIdx.x * ROWS;
    const int lane = t & 63;
    const int wave = t >> 6;
    const int quad = lane >> 4;
    const int lr = lane & 15;

    // ---- Phase 1: x -> bf16 LDS (cvt_pk, 1 inst / 2 values) ----
    {
        const int row = row0 + t;
        const float4* ar = (const float4*)(A + (size_t)row * 32);
        const float4* sr = (const float4*)(S + (size_t)row * 32);
        #pragma unroll
        for (int i = 0; i < 4; ++i) {
            float4 v0 = ar[2 * i], v1 = ar[2 * i + 1];
            uint4 u;
            u.x = pk2(v0.x, v0.y); u.y = pk2(v0.z, v0.w);
            u.z = pk2(v1.x, v1.y); u.w = pk2(v1.z, v1.w);
            *(uint4*)&xs[t][i * 8] = u;
        }
        #pragma unroll
        for (int i = 0; i < 4; ++i) {
            float4 v0 = sr[2 * i], v1 = sr[2 * i + 1];
            uint4 u;
            u.x = pk2(v0.x, v0.y); u.y = pk2(v0.z, v0.w);
            u.z = pk2(v1.x, v1.y); u.w = pk2(v1.z, v1.w);
            *(uint4*)&xs[t][32 + i * 8] = u;
        }
    }
    // Wave-local ordering: this wave's 64 lanes wrote rows [wave*64, wave*64+64);
    // gating below reads exactly those rows -> no __syncthreads needed, but the
    // cross-lane LDS writes must drain before any read (rule #18).
    asm volatile("s_waitcnt lgkmcnt(0)" ::: "memory");
    __builtin_amdgcn_sched_barrier(0);

    // ---- Phase 1.5: gating, transposed (gh^T = gw1^T · S^T), register-only ----
    // C/D of mfma(gf, sb): lane lr gets gh[m=lr][g = quad*4+r] (acc0) / [16+quad*4+r] (acc1)
    // -> L2 input is pre-distributed per lane; no LDS transpose, no intra-loop barriers.
    {
        const short* gwf = wf + 32768;
        bf16x8 gf0 = *(const bf16x8*)(gwf + (size_t)lane * 8);         // gw1^T rows g=0..15
        bf16x8 gf1 = *(const bf16x8*)(gwf + 512 + (size_t)lane * 8);   // rows g=16..31
        // per-lane gw2 slice: rows g = quad*4+j (j<4) and 16+quad*4+(j-4) (j>=4)
        float gw2r[8][8];
        #pragma unroll
        for (int j = 0; j < 4; ++j) {
            float4 a0 = *(const float4*)(gw2 + (quad * 4 + j) * 8);
            float4 a1 = *(const float4*)(gw2 + (quad * 4 + j) * 8 + 4);
            gw2r[j][0] = a0.x; gw2r[j][1] = a0.y; gw2r[j][2] = a0.z; gw2r[j][3] = a0.w;
            gw2r[j][4] = a1.x; gw2r[j][5] = a1.y; gw2r[j][6] = a1.z; gw2r[j][7] = a1.w;
            float4 b0 = *(const float4*)(gw2 + (16 + quad * 4 + j) * 8);
            float4 b1 = *(const float4*)(gw2 + (16 + quad * 4 + j) * 8 + 4);
            gw2r[4 + j][0] = b0.x; gw2r[4 + j][1] = b0.y; gw2r[4 + j][2] = b0.z; gw2r[4 + j][3] = b0.w;
            gw2r[4 + j][4] = b1.x; gw2r[4 + j][5] = b1.y; gw2r[4 + j][6] = b1.z; gw2r[4 + j][7] = b1.w;
        }
        // gb1 folded into accumulator init: acc row = g
        const f32x4 binit0 = *(const f32x4*)(gb1 + quad * 4);
        const f32x4 binit1 = *(const f32x4*)(gb1 + 16 + quad * 4);
        float gb2v[8];
        #pragma unroll
        for (int e = 0; e < 8; ++e) gb2v[e] = gb2[e];
        const int a16 = (lane ^ 16) << 2;
        const int a32 = (lane ^ 32) << 2;

        #pragma unroll 1
        for (int i = 0; i < 4; ++i) {
            const int rt = wave * 4 + i;
            // B-frag = S^T: identical bytes/layout to the expert A-frag read
            bf16x8 sb = *(const bf16x8*)&xs[rt * 16 + lr][32 + quad * 8];
            f32x4 acc0 = binit0, acc1 = binit1;
            acc0 = __builtin_amdgcn_mfma_f32_16x16x32_bf16(gf0, sb, acc0, 0, 0, 0);
            acc1 = __builtin_amdgcn_mfma_f32_16x16x32_bf16(gf1, sb, acc1, 0, 0, 0);
            // L2 partials: lane owns row m=lr, 8 g-values
            float lg[8];
            #pragma unroll
            for (int e = 0; e < 8; ++e) lg[e] = 0.f;
            #pragma unroll
            for (int r = 0; r < 4; ++r) {
                float v = fmaxf(acc0[r], 0.f);
                #pragma unroll
                for (int e = 0; e < 8; ++e) lg[e] = fmaf(v, gw2r[r][e], lg[e]);
            }
            #pragma unroll
            for (int r = 0; r < 4; ++r) {
                float v = fmaxf(acc1[r], 0.f);
                #pragma unroll
                for (int e = 0; e < 8; ++e) lg[e] = fmaf(v, gw2r[4 + r][e], lg[e]);
            }
            // reduce partials across the 4 quads (xor16 then xor32)
            #pragma unroll
            for (int e = 0; e < 8; ++e) {
                float v = bperm_add(lg[e], a16);
                v = bperm_add(v, a32);
                lg[e] = v + gb2v[e];
            }
            // softmax (16 rows in parallel across lr lanes; quads redundant)
            float mx = fmaxf(fmaxf(fmaxf(lg[0], lg[1]), fmaxf(lg[2], lg[3])),
                             fmaxf(fmaxf(lg[4], lg[5]), fmaxf(lg[6], lg[7])));
            float pv[8], sum = 0.f;
            #pragma unroll
            for (int e = 0; e < 8; ++e) { pv[e] = __expf(lg[e] - mx); sum += pv[e]; }
            const float inv = __builtin_amdgcn_rcpf(sum);
            if (quad == 0) {
                uint4 u;
                u.x = pk2(pv[0] * inv, pv[1] * inv);
                u.y = pk2(pv[2] * inv, pv[3] * inv);
                u.z = pk2(pv[4] * inv, pv[5] * inv);
                u.w = pk2(pv[6] * inv, pv[7] * inv);
                *(uint4*)&psb[rt * 16 + lr][0] = u;
            }
        }
    }

    // ---- Load expert B fragments + per-column w2/b1 ----
    bf16x8 blo[8], bhi[8];
    float w2p[8], b1c[8];
    const int e0 = wave * 2;
    #pragma unroll
    for (int tt = 0; tt < 8; ++tt) {
        const short* base = wf + ((size_t)((wave * 8 + tt) * 128) + lane) * 8;
        blo[tt] = *(const bf16x8*)base;
        bhi[tt] = *(const bf16x8*)(base + 512);
        int n = wave * 128 + tt * 16 + lr;
        int e = n >> 6, h = n & 63;
        w2p[tt] = ew2[e * HH + h];
        b1c[tt] = eb1[e * HH + h];
    }
    const float ebi0 = eb2[e0] * 0.0625f;        // eb2 folded into per-lane partial init
    const float ebi1 = eb2[e0 + 1] * 0.0625f;    // (16 lanes sum to eb2[e])

    __syncthreads();

    // ---- Phase 2: expert MFMA over 16-row tiles ----
    #pragma unroll 1
    for (int rt = 0; rt < ROWS / 16; ++rt) {
        const short* xp = &xs[rt * 16 + lr][quad * 8];
        bf16x8 alo = *(const bf16x8*)xp;          // k in [0,32)
        bf16x8 ahi = *(const bf16x8*)(xp + 32);   // k in [32,64)
        f32x4 acc[8];
        #pragma unroll
        for (int tt = 0; tt < 8; ++tt)            // bias pre-loaded into accumulator
            acc[tt] = (f32x4){b1c[tt], b1c[tt], b1c[tt], b1c[tt]};
        #pragma unroll
        for (int tt = 0; tt < 8; ++tt)
            acc[tt] = __builtin_amdgcn_mfma_f32_16x16x32_bf16(alo, blo[tt], acc[tt], 0, 0, 0);
        #pragma unroll
        for (int tt = 0; tt < 8; ++tt)
            acc[tt] = __builtin_amdgcn_mfma_f32_16x16x32_bf16(ahi, bhi[tt], acc[tt], 0, 0, 0);

        // epilogue: relu, fold w2, per-expert partials (4 tiles each)
        float pe0[4] = {ebi0, ebi0, ebi0, ebi0};
        float pe1[4] = {ebi1, ebi1, ebi1, ebi1};
        #pragma unroll
        for (int tt = 0; tt < 8; ++tt) {
            #pragma unroll
            for (int r = 0; r < 4; ++r) {
                float v = fmaxf(acc[tt][r], 0.0f);
                if (tt < 4) pe0[r] = fmaf(v, w2p[tt], pe0[r]);
                else        pe1[r] = fmaf(v, w2p[tt], pe1[r]);
            }
        }
        #pragma unroll
        for (int r = 0; r < 4; ++r) {
            const int rw = rt * 16 + quad * 4 + r;   // C/D row = quad*4+reg
            float c = fmaf(pe0[r], bf2f(psb[rw][e0]), pe1[r] * bf2f(psb[rw][e0 + 1]));
            c = dpp_add<0xB1>(c);                 // quad_perm xor 1
            c = dpp_add<0x4E>(c);                 // quad_perm xor 2
            c = dpp_add<0x124>(c);                // row_ror:4
            c = dpp_add<0x128>(c);                // row_ror:8
            if (lr == 0) *(float*)&xs[rw][64 + 2 * wave] = c;   // private slot, no atomic
        }
    }

    __syncthreads();
    const float4 fs = *(const float4*)&xs[t][64];
    out[row0 + t] = (fs.x + fs.y) + (fs.z + fs.w);
}

extern "C" void kernel_launch(void* const* d_in, const int* in_sizes, int n_in,
                              void* d_out, int out_size, void* d_ws, size_t ws_size,
                              hipStream_t stream) {
    const float* A   = (const float*)d_in[0];
    const float* S   = (const float*)d_in[1];
    const float* gw1 = (const float*)d_in[2];
    const float* gb1 = (const float*)d_in[3];
    const float* gw2 = (const float*)d_in[4];
    const float* gb2 = (const float*)d_in[5];
    const float* ew1 = (const float*)d_in[6];
    const float* eb1 = (const float*)d_in[7];
    const float* ew2 = (const float*)d_in[8];
    const float* eb2 = (const float*)d_in[9];
    float* out = (float*)d_out;
    short* wf = (short*)d_ws;   // 64 KB expert W1 frags + 2 KB gating gw1^T frags

    const int B = in_sizes[0] / 32;
    hipLaunchKernelGGL(prep_kernel, dim3(16), dim3(256), 0, stream, ew1, gw1, wf);
    hipLaunchKernelGGL(moe_kernel, dim3(B / ROWS), dim3(256), 0, stream,
                       A, S, gb1, gw2, gb2, wf, eb1, ew2, eb2, out);
}

// Round 4
// 195.653 us; speedup vs baseline: 1.5008x; 1.5008x over previous
//
#include <hip/hip_runtime.h>
#include <hip/hip_bf16.h>
#include <math.h>

#define ROWS 256
#define DD 64
#define EE 8
#define HH 64
#define GHD 32

typedef __attribute__((ext_vector_type(8))) short bf16x8;
typedef __attribute__((ext_vector_type(4))) float f32x4;

static __device__ __forceinline__ short f2bf(float f) {
    unsigned u = __builtin_bit_cast(unsigned, f);
    unsigned r = (u + 0x7fffu + ((u >> 16) & 1u)) >> 16;  // round-to-nearest-even
    return (short)r;
}
static __device__ __forceinline__ float bf2f(unsigned short b) {
    unsigned u = ((unsigned)b) << 16;
    return __builtin_bit_cast(float, u);
}
// packed f32x2 -> bf16x2 (lowers to v_cvt_pk_bf16_f32, RNE — bit-identical to f2bf)
static __device__ __forceinline__ unsigned pk2(float lo, float hi) {
    __hip_bfloat162 h = __float22bfloat162_rn(make_float2(lo, hi));
    unsigned r;
    __builtin_memcpy(&r, &h, 4);
    return r;
}
// butterfly add via DPP (ctrl must be a compile-time constant)
template <int CTRL>
static __device__ __forceinline__ float dpp_add(float x) {
    int xi = __builtin_bit_cast(int, x);
    int yi = __builtin_amdgcn_update_dpp(0, xi, CTRL, 0xF, 0xF, true);
    return x + __builtin_bit_cast(float, yi);
}
// cross-lane add via ds_bpermute (addr = (lane^mask)<<2, precomputed)
static __device__ __forceinline__ float bperm_add(float x, int addr) {
    int xi = __builtin_bit_cast(int, x);
    int yi = __builtin_amdgcn_ds_bpermute(addr, xi);
    return x + __builtin_bit_cast(float, yi);
}

// Precompute W1 (experts) and gw1 (gating) as bf16 MFMA fragments in d_ws.
// expert frags (B-operand): idx = wave<<10 | tt<<7 | half<<6 | lane, 8 shorts each (64 KB)
// gating frags (A-operand of gw1^T): 2 tiles x 64 lanes x 8 shorts at short-offset 32768 (2 KB)
//   A[row=g][k=d] = gw1[d][g]; lane l holds row g = tile*16 + (l&15), k = (l>>4)*8+j.
// d_ws must be >= 67584 bytes.
__global__ __launch_bounds__(256) void prep_kernel(const float* __restrict__ ew1,
                                                   const float* __restrict__ gw1,
                                                   short* __restrict__ wf) {
    int idx = blockIdx.x * 256 + threadIdx.x;   // 4096 frags
    int lane = idx & 63;
    int half = (idx >> 6) & 1;
    int tt   = (idx >> 7) & 7;
    int wave = (idx >> 10) & 3;
    int n = wave * 128 + tt * 16 + (lane & 15);
    int e = n >> 6, h = n & 63;
    int quad = lane >> 4;
    short v[8];
    #pragma unroll
    for (int j = 0; j < 8; ++j) {
        int dl = quad * 8 + j + half * 32;
        v[j] = f2bf(ew1[(e * DD + dl) * HH + h]);
    }
    *(bf16x8*)(wf + (size_t)idx * 8) = *(const bf16x8*)v;
    if (idx < 128) {                            // gw1^T A-frags
        int tile = idx >> 6;
        int lr = lane & 15;
        short g[8];
        #pragma unroll
        for (int j = 0; j < 8; ++j)
            g[j] = f2bf(gw1[(quad * 8 + j) * GHD + tile * 16 + lr]);
        *(bf16x8*)(wf + 32768 + (size_t)idx * 8) = *(const bf16x8*)g;
    }
}

__global__ __launch_bounds__(256, 3) void moe_kernel(
    const float* __restrict__ A, const float* __restrict__ S,
    const float* __restrict__ gb1, const float* __restrict__ gw2,
    const float* __restrict__ gb2, const short* __restrict__ wf,
    const float* __restrict__ eb1, const float* __restrict__ ew2,
    const float* __restrict__ eb2, float* __restrict__ out)
{
    // xs row = 72 shorts (144 B): [0..63] bf16 x-data, [64..71] = 4 f32 result slots (1/wave).
    __shared__ __align__(16) short xs[ROWS][72];            // 36864 B
    __shared__ __align__(16) unsigned short psb[ROWS][EE];  // 4096 B (bf16 gating probs)
    // total 40960 B -> LDS allows 4 blocks/CU (VGPR may cap at 3)

    const int t = threadIdx.x;
    const int row0 = blockIdx.x * ROWS;
    const int lane = t & 63;
    const int wave = t >> 6;
    const int quad = lane >> 4;
    const int lr = lane & 15;

    // ---- Phase 1: x -> bf16 LDS (cvt_pk, 1 inst / 2 values) ----
    {
        const int row = row0 + t;
        const float4* ar = (const float4*)(A + (size_t)row * 32);
        const float4* sr = (const float4*)(S + (size_t)row * 32);
        #pragma unroll
        for (int i = 0; i < 4; ++i) {
            float4 v0 = ar[2 * i], v1 = ar[2 * i + 1];
            uint4 u;
            u.x = pk2(v0.x, v0.y); u.y = pk2(v0.z, v0.w);
            u.z = pk2(v1.x, v1.y); u.w = pk2(v1.z, v1.w);
            *(uint4*)&xs[t][i * 8] = u;
        }
        #pragma unroll
        for (int i = 0; i < 4; ++i) {
            float4 v0 = sr[2 * i], v1 = sr[2 * i + 1];
            uint4 u;
            u.x = pk2(v0.x, v0.y); u.y = pk2(v0.z, v0.w);
            u.z = pk2(v1.x, v1.y); u.w = pk2(v1.z, v1.w);
            *(uint4*)&xs[t][32 + i * 8] = u;
        }
    }
    // Wave-local ordering: this wave's 64 lanes wrote rows [wave*64, wave*64+64);
    // gating below reads exactly those rows -> no __syncthreads needed, but the
    // cross-lane LDS writes must drain before any read (rule #18).
    asm volatile("s_waitcnt lgkmcnt(0)" ::: "memory");
    __builtin_amdgcn_sched_barrier(0);

    // ---- Phase 1.5: gating, transposed (gh^T = gw1^T · S^T), register-only ----
    // C/D of mfma(gf, sb): lane lr gets gh[m=lr][g = quad*4+r] (acc0) / [16+quad*4+r] (acc1)
    // -> L2 input is pre-distributed per lane; no LDS transpose, no intra-loop barriers.
    {
        const short* gwf = wf + 32768;
        bf16x8 gf0 = *(const bf16x8*)(gwf + (size_t)lane * 8);         // gw1^T rows g=0..15
        bf16x8 gf1 = *(const bf16x8*)(gwf + 512 + (size_t)lane * 8);   // rows g=16..31
        // per-lane gw2 slice: rows g = quad*4+j (j<4) and 16+quad*4+(j-4) (j>=4)
        float gw2r[8][8];
        #pragma unroll
        for (int j = 0; j < 4; ++j) {
            float4 a0 = *(const float4*)(gw2 + (quad * 4 + j) * 8);
            float4 a1 = *(const float4*)(gw2 + (quad * 4 + j) * 8 + 4);
            gw2r[j][0] = a0.x; gw2r[j][1] = a0.y; gw2r[j][2] = a0.z; gw2r[j][3] = a0.w;
            gw2r[j][4] = a1.x; gw2r[j][5] = a1.y; gw2r[j][6] = a1.z; gw2r[j][7] = a1.w;
            float4 b0 = *(const float4*)(gw2 + (16 + quad * 4 + j) * 8);
            float4 b1 = *(const float4*)(gw2 + (16 + quad * 4 + j) * 8 + 4);
            gw2r[4 + j][0] = b0.x; gw2r[4 + j][1] = b0.y; gw2r[4 + j][2] = b0.z; gw2r[4 + j][3] = b0.w;
            gw2r[4 + j][4] = b1.x; gw2r[4 + j][5] = b1.y; gw2r[4 + j][6] = b1.z; gw2r[4 + j][7] = b1.w;
        }
        // gb1 folded into accumulator init: acc row = g
        const f32x4 binit0 = *(const f32x4*)(gb1 + quad * 4);
        const f32x4 binit1 = *(const f32x4*)(gb1 + 16 + quad * 4);
        float gb2v[8];
        #pragma unroll
        for (int e = 0; e < 8; ++e) gb2v[e] = gb2[e];
        const int a16 = (lane ^ 16) << 2;
        const int a32 = (lane ^ 32) << 2;

        #pragma unroll 1
        for (int i = 0; i < 4; ++i) {
            const int rt = wave * 4 + i;
            // B-frag = S^T: identical bytes/layout to the expert A-frag read
            bf16x8 sb = *(const bf16x8*)&xs[rt * 16 + lr][32 + quad * 8];
            f32x4 acc0 = binit0, acc1 = binit1;
            acc0 = __builtin_amdgcn_mfma_f32_16x16x32_bf16(gf0, sb, acc0, 0, 0, 0);
            acc1 = __builtin_amdgcn_mfma_f32_16x16x32_bf16(gf1, sb, acc1, 0, 0, 0);
            // L2 partials: lane owns row m=lr, 8 g-values
            float lg[8];
            #pragma unroll
            for (int e = 0; e < 8; ++e) lg[e] = 0.f;
            #pragma unroll
            for (int r = 0; r < 4; ++r) {
                float v = fmaxf(acc0[r], 0.f);
                #pragma unroll
                for (int e = 0; e < 8; ++e) lg[e] = fmaf(v, gw2r[r][e], lg[e]);
            }
            #pragma unroll
            for (int r = 0; r < 4; ++r) {
                float v = fmaxf(acc1[r], 0.f);
                #pragma unroll
                for (int e = 0; e < 8; ++e) lg[e] = fmaf(v, gw2r[4 + r][e], lg[e]);
            }
            // reduce partials across the 4 quads (xor16 then xor32)
            #pragma unroll
            for (int e = 0; e < 8; ++e) {
                float v = bperm_add(lg[e], a16);
                v = bperm_add(v, a32);
                lg[e] = v + gb2v[e];
            }
            // softmax (16 rows in parallel across lr lanes; quads redundant)
            float mx = fmaxf(fmaxf(fmaxf(lg[0], lg[1]), fmaxf(lg[2], lg[3])),
                             fmaxf(fmaxf(lg[4], lg[5]), fmaxf(lg[6], lg[7])));
            float pv[8], sum = 0.f;
            #pragma unroll
            for (int e = 0; e < 8; ++e) { pv[e] = __expf(lg[e] - mx); sum += pv[e]; }
            const float inv = __builtin_amdgcn_rcpf(sum);
            if (quad == 0) {
                uint4 u;
                u.x = pk2(pv[0] * inv, pv[1] * inv);
                u.y = pk2(pv[2] * inv, pv[3] * inv);
                u.z = pk2(pv[4] * inv, pv[5] * inv);
                u.w = pk2(pv[6] * inv, pv[7] * inv);
                *(uint4*)&psb[rt * 16 + lr][0] = u;
            }
        }
    }

    // ---- Load expert B fragments + per-column w2/b1 ----
    bf16x8 blo[8], bhi[8];
    float w2p[8], b1c[8];
    const int e0 = wave * 2;
    #pragma unroll
    for (int tt = 0; tt < 8; ++tt) {
        const short* base = wf + ((size_t)((wave * 8 + tt) * 128) + lane) * 8;
        blo[tt] = *(const bf16x8*)base;
        bhi[tt] = *(const bf16x8*)(base + 512);
        int n = wave * 128 + tt * 16 + lr;
        int e = n >> 6, h = n & 63;
        w2p[tt] = ew2[e * HH + h];
        b1c[tt] = eb1[e * HH + h];
    }
    const float ebi0 = eb2[e0] * 0.0625f;        // eb2 folded into per-lane partial init
    const float ebi1 = eb2[e0 + 1] * 0.0625f;    // (16 lanes sum to eb2[e])

    __syncthreads();

    // ---- Phase 2: expert MFMA over 16-row tiles ----
    #pragma unroll 1
    for (int rt = 0; rt < ROWS / 16; ++rt) {
        const short* xp = &xs[rt * 16 + lr][quad * 8];
        bf16x8 alo = *(const bf16x8*)xp;          // k in [0,32)
        bf16x8 ahi = *(const bf16x8*)(xp + 32);   // k in [32,64)
        f32x4 acc[8];
        #pragma unroll
        for (int tt = 0; tt < 8; ++tt)            // bias pre-loaded into accumulator
            acc[tt] = (f32x4){b1c[tt], b1c[tt], b1c[tt], b1c[tt]};
        #pragma unroll
        for (int tt = 0; tt < 8; ++tt)
            acc[tt] = __builtin_amdgcn_mfma_f32_16x16x32_bf16(alo, blo[tt], acc[tt], 0, 0, 0);
        #pragma unroll
        for (int tt = 0; tt < 8; ++tt)
            acc[tt] = __builtin_amdgcn_mfma_f32_16x16x32_bf16(ahi, bhi[tt], acc[tt], 0, 0, 0);

        // epilogue: relu, fold w2, per-expert partials (4 tiles each)
        float pe0[4] = {ebi0, ebi0, ebi0, ebi0};
        float pe1[4] = {ebi1, ebi1, ebi1, ebi1};
        #pragma unroll
        for (int tt = 0; tt < 8; ++tt) {
            #pragma unroll
            for (int r = 0; r < 4; ++r) {
                float v = fmaxf(acc[tt][r], 0.0f);
                if (tt < 4) pe0[r] = fmaf(v, w2p[tt], pe0[r]);
                else        pe1[r] = fmaf(v, w2p[tt], pe1[r]);
            }
        }
        #pragma unroll
        for (int r = 0; r < 4; ++r) {
            const int rw = rt * 16 + quad * 4 + r;   // C/D row = quad*4+reg
            float c = fmaf(pe0[r], bf2f(psb[rw][e0]), pe1[r] * bf2f(psb[rw][e0 + 1]));
            c = dpp_add<0xB1>(c);                 // quad_perm xor 1
            c = dpp_add<0x4E>(c);                 // quad_perm xor 2
            c = dpp_add<0x124>(c);                // row_ror:4
            c = dpp_add<0x128>(c);                // row_ror:8
            if (lr == 0) *(float*)&xs[rw][64 + 2 * wave] = c;   // private slot, no atomic
        }
    }

    __syncthreads();
    const float4 fs = *(const float4*)&xs[t][64];
    out[row0 + t] = (fs.x + fs.y) + (fs.z + fs.w);
}

extern "C" void kernel_launch(void* const* d_in, const int* in_sizes, int n_in,
                              void* d_out, int out_size, void* d_ws, size_t ws_size,
                              hipStream_t stream) {
    const float* A   = (const float*)d_in[0];
    const float* S   = (const float*)d_in[1];
    const float* gw1 = (const float*)d_in[2];
    const float* gb1 = (const float*)d_in[3];
    const float* gw2 = (const float*)d_in[4];
    const float* gb2 = (const float*)d_in[5];
    const float* ew1 = (const float*)d_in[6];
    const float* eb1 = (const float*)d_in[7];
    const float* ew2 = (const float*)d_in[8];
    const float* eb2 = (const float*)d_in[9];
    float* out = (float*)d_out;
    short* wf = (short*)d_ws;   // 64 KB expert W1 frags + 2 KB gating gw1^T frags

    const int B = in_sizes[0] / 32;
    hipLaunchKernelGGL(prep_kernel, dim3(16), dim3(256), 0, stream, ew1, gw1, wf);
    hipLaunchKernelGGL(moe_kernel, dim3(B / ROWS), dim3(256), 0, stream,
                       A, S, gb1, gw2, gb2, wf, eb1, ew2, eb2, out);
}

// Round 5
// 190.152 us; speedup vs baseline: 1.5442x; 1.0289x over previous
//
#include <hip/hip_runtime.h>
#include <hip/hip_bf16.h>
#include <math.h>

#define ROWS 256
#define DD 64
#define EE 8
#define HH 64
#define GHD 32

typedef __attribute__((ext_vector_type(8))) short bf16x8;
typedef __attribute__((ext_vector_type(4))) float f32x4;

static __device__ __forceinline__ short f2bf(float f) {
    unsigned u = __builtin_bit_cast(unsigned, f);
    unsigned r = (u + 0x7fffu + ((u >> 16) & 1u)) >> 16;  // round-to-nearest-even
    return (short)r;
}
// packed f32x2 -> bf16x2 (lowers to v_cvt_pk_bf16_f32, RNE — bit-identical to f2bf)
static __device__ __forceinline__ unsigned pk2(float lo, float hi) {
    __hip_bfloat162 h = __float22bfloat162_rn(make_float2(lo, hi));
    unsigned r;
    __builtin_memcpy(&r, &h, 4);
    return r;
}
// cross-lane add via ds_bpermute (addr = (lane^mask)<<2, precomputed)
static __device__ __forceinline__ float bperm_add(float x, int addr) {
    int xi = __builtin_bit_cast(int, x);
    int yi = __builtin_amdgcn_ds_bpermute(addr, xi);
    return x + __builtin_bit_cast(float, yi);
}

// Precompute W1 (experts) and gw1 (gating) as bf16 MFMA fragments in d_ws.
// For 16x16x32, A-frag and B-frag lane->(index,k) maps are identical, so these
// frags serve as W1 B-operand (x·W1) or W1^T A-operand (W1^T·x^T) unchanged.
// expert frags: idx = wave<<10 | tt<<7 | half<<6 | lane, 8 shorts each (64 KB)
// gating frags (gw1^T A-operand): 2 tiles x 64 lanes x 8 shorts at short-offset 32768 (2 KB)
// d_ws must be >= 67584 bytes.
__global__ __launch_bounds__(256) void prep_kernel(const float* __restrict__ ew1,
                                                   const float* __restrict__ gw1,
                                                   short* __restrict__ wf) {
    int idx = blockIdx.x * 256 + threadIdx.x;   // 4096 frags
    int lane = idx & 63;
    int half = (idx >> 6) & 1;
    int tt   = (idx >> 7) & 7;
    int wave = (idx >> 10) & 3;
    int n = wave * 128 + tt * 16 + (lane & 15);
    int e = n >> 6, h = n & 63;
    int quad = lane >> 4;
    short v[8];
    #pragma unroll
    for (int j = 0; j < 8; ++j) {
        int dl = quad * 8 + j + half * 32;
        v[j] = f2bf(ew1[(e * DD + dl) * HH + h]);
    }
    *(bf16x8*)(wf + (size_t)idx * 8) = *(const bf16x8*)v;
    if (idx < 128) {                            // gw1^T A-frags
        int tile = idx >> 6;
        int lr = lane & 15;
        short g[8];
        #pragma unroll
        for (int j = 0; j < 8; ++j)
            g[j] = f2bf(gw1[(quad * 8 + j) * GHD + tile * 16 + lr]);
        *(bf16x8*)(wf + 32768 + (size_t)idx * 8) = *(const bf16x8*)g;
    }
}

__global__ __launch_bounds__(256, 3) void moe_kernel(
    const float* __restrict__ A, const float* __restrict__ S,
    const float* __restrict__ gb1, const float* __restrict__ gw2,
    const float* __restrict__ gb2, const short* __restrict__ wf,
    const float* __restrict__ eb1, const float* __restrict__ ew2,
    const float* __restrict__ eb2, float* __restrict__ out)
{
    // xs row = 72 shorts (144 B): [0..63] bf16 x-data, [64..71] = 4 f32 result slots (1/wave).
    __shared__ __align__(16) short xs[ROWS][72];            // 36864 B
    __shared__ __align__(16) unsigned short psb[ROWS][EE];  // 4096 B (bf16 gating probs)
    // total 40960 B

    const int t = threadIdx.x;
    const int row0 = blockIdx.x * ROWS;
    const int lane = t & 63;
    const int wave = t >> 6;
    const int quad = lane >> 4;
    const int lr = lane & 15;

    // ---- Phase 1: x -> bf16 LDS (cvt_pk, 1 inst / 2 values) ----
    {
        const int row = row0 + t;
        const float4* ar = (const float4*)(A + (size_t)row * 32);
        const float4* sr = (const float4*)(S + (size_t)row * 32);
        #pragma unroll
        for (int i = 0; i < 4; ++i) {
            float4 v0 = ar[2 * i], v1 = ar[2 * i + 1];
            uint4 u;
            u.x = pk2(v0.x, v0.y); u.y = pk2(v0.z, v0.w);
            u.z = pk2(v1.x, v1.y); u.w = pk2(v1.z, v1.w);
            *(uint4*)&xs[t][i * 8] = u;
        }
        #pragma unroll
        for (int i = 0; i < 4; ++i) {
            float4 v0 = sr[2 * i], v1 = sr[2 * i + 1];
            uint4 u;
            u.x = pk2(v0.x, v0.y); u.y = pk2(v0.z, v0.w);
            u.z = pk2(v1.x, v1.y); u.w = pk2(v1.z, v1.w);
            *(uint4*)&xs[t][32 + i * 8] = u;
        }
    }
    // Wave-local ordering: this wave's 64 lanes wrote rows [wave*64, wave*64+64);
    // gating below reads exactly those rows -> no __syncthreads needed, but the
    // cross-lane LDS writes must drain before any read (rule #18).
    asm volatile("s_waitcnt lgkmcnt(0)" ::: "memory");
    __builtin_amdgcn_sched_barrier(0);

    const int a16 = (lane ^ 16) << 2;
    const int a32 = (lane ^ 32) << 2;

    // ---- Phase 1.5: gating, transposed (gh^T = gw1^T · S^T), register-only ----
    {
        const short* gwf = wf + 32768;
        bf16x8 gf0 = *(const bf16x8*)(gwf + (size_t)lane * 8);         // gw1^T rows g=0..15
        bf16x8 gf1 = *(const bf16x8*)(gwf + 512 + (size_t)lane * 8);   // rows g=16..31
        // per-lane gw2 slice: rows g = quad*4+j (j<4) and 16+quad*4+(j-4) (j>=4)
        float gw2r[8][8];
        #pragma unroll
        for (int j = 0; j < 4; ++j) {
            float4 a0 = *(const float4*)(gw2 + (quad * 4 + j) * 8);
            float4 a1 = *(const float4*)(gw2 + (quad * 4 + j) * 8 + 4);
            gw2r[j][0] = a0.x; gw2r[j][1] = a0.y; gw2r[j][2] = a0.z; gw2r[j][3] = a0.w;
            gw2r[j][4] = a1.x; gw2r[j][5] = a1.y; gw2r[j][6] = a1.z; gw2r[j][7] = a1.w;
            float4 b0 = *(const float4*)(gw2 + (16 + quad * 4 + j) * 8);
            float4 b1 = *(const float4*)(gw2 + (16 + quad * 4 + j) * 8 + 4);
            gw2r[4 + j][0] = b0.x; gw2r[4 + j][1] = b0.y; gw2r[4 + j][2] = b0.z; gw2r[4 + j][3] = b0.w;
            gw2r[4 + j][4] = b1.x; gw2r[4 + j][5] = b1.y; gw2r[4 + j][6] = b1.z; gw2r[4 + j][7] = b1.w;
        }
        const f32x4 binit0 = *(const f32x4*)(gb1 + quad * 4);
        const f32x4 binit1 = *(const f32x4*)(gb1 + 16 + quad * 4);
        float gb2v[8];
        #pragma unroll
        for (int e = 0; e < 8; ++e) gb2v[e] = gb2[e];

        #pragma unroll 1
        for (int i = 0; i < 4; ++i) {
            const int rt = wave * 4 + i;
            // B-frag = S^T: identical bytes/layout to a row A-frag read
            bf16x8 sb = *(const bf16x8*)&xs[rt * 16 + lr][32 + quad * 8];
            f32x4 acc0 = binit0, acc1 = binit1;
            acc0 = __builtin_amdgcn_mfma_f32_16x16x32_bf16(gf0, sb, acc0, 0, 0, 0);
            acc1 = __builtin_amdgcn_mfma_f32_16x16x32_bf16(gf1, sb, acc1, 0, 0, 0);
            // L2 partials: lane owns row m=lr, 8 g-values
            float lg[8];
            #pragma unroll
            for (int e = 0; e < 8; ++e) lg[e] = 0.f;
            #pragma unroll
            for (int r = 0; r < 4; ++r) {
                float v = fmaxf(acc0[r], 0.f);
                #pragma unroll
                for (int e = 0; e < 8; ++e) lg[e] = fmaf(v, gw2r[r][e], lg[e]);
            }
            #pragma unroll
            for (int r = 0; r < 4; ++r) {
                float v = fmaxf(acc1[r], 0.f);
                #pragma unroll
                for (int e = 0; e < 8; ++e) lg[e] = fmaf(v, gw2r[4 + r][e], lg[e]);
            }
            // reduce partials across the 4 quads (xor16 then xor32)
            #pragma unroll
            for (int e = 0; e < 8; ++e) {
                float v = bperm_add(lg[e], a16);
                v = bperm_add(v, a32);
                lg[e] = v + gb2v[e];
            }
            // softmax (16 rows in parallel across lr lanes; quads redundant)
            float mx = fmaxf(fmaxf(fmaxf(lg[0], lg[1]), fmaxf(lg[2], lg[3])),
                             fmaxf(fmaxf(lg[4], lg[5]), fmaxf(lg[6], lg[7])));
            float pv[8], sum = 0.f;
            #pragma unroll
            for (int e = 0; e < 8; ++e) { pv[e] = __expf(lg[e] - mx); sum += pv[e]; }
            const float inv = __builtin_amdgcn_rcpf(sum);
            if (quad == 0) {
                uint4 u;
                u.x = pk2(pv[0] * inv, pv[1] * inv);
                u.y = pk2(pv[2] * inv, pv[3] * inv);
                u.z = pk2(pv[4] * inv, pv[5] * inv);
                u.w = pk2(pv[6] * inv, pv[7] * inv);
                *(uint4*)&psb[rt * 16 + lr][0] = u;
            }
        }
    }

    // ---- Load expert W1^T A-frags + contiguous per-(tt,quad) w2/b1 f32x4 ----
    bf16x8 blo[8], bhi[8];
    f32x4 w2q[8], b1q[8];
    const int e0 = wave * 2;
    #pragma unroll
    for (int tt = 0; tt < 8; ++tt) {
        const short* base = wf + ((size_t)((wave * 8 + tt) * 128) + lane) * 8;
        blo[tt] = *(const bf16x8*)base;
        bhi[tt] = *(const bf16x8*)(base + 512);
        const int nb = wave * 128 + tt * 16 + quad * 4;  // flat [E][H] index
        w2q[tt] = *(const f32x4*)(ew2 + nb);
        b1q[tt] = *(const f32x4*)(eb1 + nb);
    }
    const float pei0 = eb2[e0] * 0.25f;          // eb2 folded into per-quad partial init
    const float pei1 = eb2[e0 + 1] * 0.25f;      // (4 quads sum to eb2[e])

    __syncthreads();

    // ---- Phase 2: expert MFMA, transposed (eh^T = W1^T · x^T) ----
    // C/D: col = batch row (lr), row = n-within-tile (quad*4+r)
    // -> lane owns batch row rt*16+lr fully; h-reduce = per-lane FMA + 2 bperm.
    #pragma unroll 1
    for (int rt = 0; rt < ROWS / 16; ++rt) {
        const short* xp = &xs[rt * 16 + lr][quad * 8];
        bf16x8 xlo = *(const bf16x8*)xp;          // d in [0,32)
        bf16x8 xhi = *(const bf16x8*)(xp + 32);   // d in [32,64)
        f32x4 acc[8];
        #pragma unroll
        for (int tt = 0; tt < 8; ++tt)            // b1 pre-loaded into accumulator
            acc[tt] = b1q[tt];
        #pragma unroll
        for (int tt = 0; tt < 8; ++tt)
            acc[tt] = __builtin_amdgcn_mfma_f32_16x16x32_bf16(blo[tt], xlo, acc[tt], 0, 0, 0);
        #pragma unroll
        for (int tt = 0; tt < 8; ++tt)
            acc[tt] = __builtin_amdgcn_mfma_f32_16x16x32_bf16(bhi[tt], xhi, acc[tt], 0, 0, 0);

        // epilogue: relu + w2 fold, per-expert scalars (lane-local h-slice)
        float pe0 = pei0, pe1 = pei1;
        #pragma unroll
        for (int tt = 0; tt < 4; ++tt) {
            #pragma unroll
            for (int r = 0; r < 4; ++r)
                pe0 = fmaf(fmaxf(acc[tt][r], 0.0f), w2q[tt][r], pe0);
        }
        #pragma unroll
        for (int tt = 4; tt < 8; ++tt) {
            #pragma unroll
            for (int r = 0; r < 4; ++r)
                pe1 = fmaf(fmaxf(acc[tt][r], 0.0f), w2q[tt][r], pe1);
        }
        // gating probs: one dword holds both bf16 probs for this wave's experts
        const unsigned pp = *(const unsigned*)&psb[rt * 16 + lr][e0];
        const float p0 = __builtin_bit_cast(float, pp << 16);
        const float p1 = __builtin_bit_cast(float, pp & 0xffff0000u);
        float c = fmaf(pe0, p0, pe1 * p1);
        c = bperm_add(c, a16);                    // sum the 4 quads' h-slices
        c = bperm_add(c, a32);
        if (quad == 0) *(float*)&xs[rt * 16 + lr][64 + 2 * wave] = c;  // private slot
    }

    __syncthreads();
    const float4 fs = *(const float4*)&xs[t][64];
    out[row0 + t] = (fs.x + fs.y) + (fs.z + fs.w);
}

extern "C" void kernel_launch(void* const* d_in, const int* in_sizes, int n_in,
                              void* d_out, int out_size, void* d_ws, size_t ws_size,
                              hipStream_t stream) {
    const float* A   = (const float*)d_in[0];
    const float* S   = (const float*)d_in[1];
    const float* gw1 = (const float*)d_in[2];
    const float* gb1 = (const float*)d_in[3];
    const float* gw2 = (const float*)d_in[4];
    const float* gb2 = (const float*)d_in[5];
    const float* ew1 = (const float*)d_in[6];
    const float* eb1 = (const float*)d_in[7];
    const float* ew2 = (const float*)d_in[8];
    const float* eb2 = (const float*)d_in[9];
    float* out = (float*)d_out;
    short* wf = (short*)d_ws;   // 64 KB expert W1 frags + 2 KB gating gw1^T frags

    const int B = in_sizes[0] / 32;
    hipLaunchKernelGGL(prep_kernel, dim3(16), dim3(256), 0, stream, ew1, gw1, wf);
    hipLaunchKernelGGL(moe_kernel, dim3(B / ROWS), dim3(256), 0, stream,
                       A, S, gb1, gw2, gb2, wf, eb1, ew2, eb2, out);
}